// Round 5
// baseline (1317.499 us; speedup 1.0000x reference)
//
#include <hip/hip_runtime.h>
#include <hip/hip_bf16.h>

#define B_   256
#define T_   512
#define H_   128
#define G3_  384
#define VEC_ 32   // H_/4 float4 per row

// ---- tiled GEMM config ----
#define TM   128
#define TN   128
#define TK   32
#define LDA  132   // padded leading dim (floats); 132*4=528 B keeps b128 16B-aligned

__device__ __forceinline__ float sigmoid_f(float x) {
    return 1.0f / (1.0f + __expf(-x));
}
__device__ __forceinline__ float tanh_f(float x) {
    return 1.0f - 2.0f / (__expf(2.0f * x) + 1.0f);
}

// ---------------------------------------------------------------------------
// gx GEMM: gx[m][n] = dot(X[m], W[n]) + bias[n].  M x 384, K = 128.
// (unchanged — 128x128 tile, double-buffered LDS, 8x8 micro-tile)
// ---------------------------------------------------------------------------
template<bool GATHER>
__global__ __launch_bounds__(256, 2)
void gx_gemm(const float* __restrict__ X,
             const int*   __restrict__ idx,
             const float* __restrict__ emb,
             const float* __restrict__ W,     // [384,128] row-major (W[n][k])
             const float* __restrict__ bias,  // [384]
             float*       __restrict__ gx)    // [M,384]
{
    __shared__ __align__(16) float As[2][TK][LDA];
    __shared__ __align__(16) float Bs[2][TK][LDA];

    const int tid = threadIdx.x;
    const int tn  = tid & 15;
    const int tm  = tid >> 4;
    const int n0  = blockIdx.x * TN;
    const int m0  = blockIdx.y * TM;

    const int q  = tid & 7;
    const float* rowA[4];
    const float* rowB[4];
#pragma unroll
    for (int s = 0; s < 4; s++) {
        const int r = (tid >> 3) + 32 * s;
        rowA[s] = GATHER ? (emb + (size_t)idx[m0 + r] * H_)
                         : (X + (size_t)(m0 + r) * H_);
        rowB[s] = W + (size_t)(n0 + r) * H_;
    }

    float4 stA[4], stB[4];
    auto load_chunk = [&](int kc) {
#pragma unroll
        for (int s = 0; s < 4; s++) {
            stA[s] = *(const float4*)(rowA[s] + kc + q * 4);
            stB[s] = *(const float4*)(rowB[s] + kc + q * 4);
        }
    };
    auto store_chunk = [&](int buf) {
#pragma unroll
        for (int s = 0; s < 4; s++) {
            const int r = (tid >> 3) + 32 * s;
#pragma unroll
            for (int d = 0; d < 4; d++) {
                As[buf][q * 4 + d][r] = ((const float*)&stA[s])[d];
                Bs[buf][q * 4 + d][r] = ((const float*)&stB[s])[d];
            }
        }
    };

    float4 acc[2][2][4];
#pragma unroll
    for (int a = 0; a < 2; a++)
#pragma unroll
        for (int b = 0; b < 2; b++)
#pragma unroll
            for (int c = 0; c < 4; c++) acc[a][b][c] = make_float4(0.f, 0.f, 0.f, 0.f);

    load_chunk(0);
    store_chunk(0);
    __syncthreads();

    for (int c = 0; c < 4; c++) {
        if (c < 3) load_chunk((c + 1) * TK);
        const int buf = c & 1;
#pragma unroll 4
        for (int k = 0; k < TK; k++) {
            float4 a0 = *(const float4*)&As[buf][k][tm * 4];
            float4 a1 = *(const float4*)&As[buf][k][64 + tm * 4];
            float4 b0 = *(const float4*)&Bs[buf][k][tn * 4];
            float4 b1 = *(const float4*)&Bs[buf][k][64 + tn * 4];
            float4 av[2] = {a0, a1}, bv[2] = {b0, b1};
#pragma unroll
            for (int mg = 0; mg < 2; mg++)
#pragma unroll
                for (int mi = 0; mi < 4; mi++) {
                    const float am = ((const float*)&av[mg])[mi];
#pragma unroll
                    for (int ng = 0; ng < 2; ng++) {
                        acc[mg][ng][mi].x = fmaf(am, bv[ng].x, acc[mg][ng][mi].x);
                        acc[mg][ng][mi].y = fmaf(am, bv[ng].y, acc[mg][ng][mi].y);
                        acc[mg][ng][mi].z = fmaf(am, bv[ng].z, acc[mg][ng][mi].z);
                        acc[mg][ng][mi].w = fmaf(am, bv[ng].w, acc[mg][ng][mi].w);
                    }
                }
        }
        if (c < 3) {
            store_chunk(buf ^ 1);
            __syncthreads();
        }
    }

    const float4 bb0 = *(const float4*)(bias + n0 + tn * 4);
    const float4 bb1 = *(const float4*)(bias + n0 + 64 + tn * 4);
#pragma unroll
    for (int mg = 0; mg < 2; mg++)
#pragma unroll
        for (int mi = 0; mi < 4; mi++) {
            const int m = m0 + mg * 64 + tm * 4 + mi;
            float* dst = gx + (size_t)m * G3_ + n0;
            float4 v0 = acc[mg][0][mi];
            v0.x += bb0.x; v0.y += bb0.y; v0.z += bb0.z; v0.w += bb0.w;
            float4 v1 = acc[mg][1][mi];
            v1.x += bb1.x; v1.y += bb1.y; v1.z += bb1.z; v1.w += bb1.w;
            *(float4*)(dst + tn * 4) = v0;
            *(float4*)(dst + 64 + tn * 4) = v1;
        }
}

// ---------------------------------------------------------------------------
// GRU recurrence, one block per batch row. Thread j owns W_hh row j in regs.
//
// R4 learning: __launch_bounds__(384,1) was a NO-OP (one resident 6-wave
// block already forces 2 waves on some EUs, so min=1 constrains nothing) —
// VGPR_Count stayed 84 = 512/6, i.e. the allocator budgets for its DEFAULT
// 6-waves/EU occupancy target and sinks the w[] loads into the loop.
// amdgpu_waves_per_eu(1,2) sets the occupancy range the allocator must
// honor: budget 512/2 = 256 VGPRs >= ~180 needed for w-resident state.
// Grid is 256 blocks = 1/CU, so occupancy past 1 block is unreachable anyway.
// ---------------------------------------------------------------------------
template<bool STORE_H, bool FINAL>
__global__
__attribute__((amdgpu_flat_work_group_size(384, 384), amdgpu_waves_per_eu(1, 2)))
void gru_rec(const float* __restrict__ gx,   // [B,T,384]
             const float* __restrict__ Whh,  // [384,128]
             const float* __restrict__ bhh,  // [384]
             float*       __restrict__ hseq, // [B,T,128] if STORE_H
             const float* __restrict__ fc_w, // [3,128]  if FINAL
             const float* __restrict__ fc_b, // [3]      if FINAL
             float*       __restrict__ out)  // [B,3]    if FINAL
{
    __shared__ __align__(16) float hbuf[H_];
    __shared__ float s_rz[2 * H_];
    __shared__ float x_n[H_];
    __shared__ float h_n[H_];

    const int j = threadIdx.x;
    const int b = blockIdx.x;

    float4 w[VEC_];
    {
        const float4* wrow = (const float4*)(Whh + (size_t)j * H_);
#pragma unroll
        for (int i = 0; i < VEC_; i++) w[i] = wrow[i];
    }
    const float bj = bhh[j];

    if (j < H_) hbuf[j] = 0.0f;
    __syncthreads();

    const float* grow = gx + (size_t)b * T_ * G3_ + j;
    const float4* hv = (const float4*)hbuf;

    float gpre[4];
#pragma unroll
    for (int u = 0; u < 4; u++) gpre[u] = grow[u * G3_];

    for (int t0 = 0; t0 < T_; t0 += 4) {
        float gcur[4];
#pragma unroll
        for (int u = 0; u < 4; u++) gcur[u] = gpre[u];
        if (t0 + 4 < T_) {
#pragma unroll
            for (int u = 0; u < 4; u++) gpre[u] = grow[(t0 + 4 + u) * G3_];
        }
#pragma unroll
        for (int u = 0; u < 4; u++) {
            const int t = t0 + u;

            // ---- inlined 128-dot, 4 independent chains, w[] const-indexed ----
            float a0 = 0.f, a1 = 0.f, a2 = 0.f, a3 = 0.f;
#pragma unroll
            for (int i = 0; i < VEC_; i += 4) {
                float4 x0 = hv[i], x1 = hv[i + 1], x2 = hv[i + 2], x3 = hv[i + 3];
                a0 = fmaf(x0.x, w[i].x, a0);     a0 = fmaf(x0.y, w[i].y, a0);
                a0 = fmaf(x0.z, w[i].z, a0);     a0 = fmaf(x0.w, w[i].w, a0);
                a1 = fmaf(x1.x, w[i+1].x, a1);   a1 = fmaf(x1.y, w[i+1].y, a1);
                a1 = fmaf(x1.z, w[i+1].z, a1);   a1 = fmaf(x1.w, w[i+1].w, a1);
                a2 = fmaf(x2.x, w[i+2].x, a2);   a2 = fmaf(x2.y, w[i+2].y, a2);
                a2 = fmaf(x2.z, w[i+2].z, a2);   a2 = fmaf(x2.w, w[i+2].w, a2);
                a3 = fmaf(x3.x, w[i+3].x, a3);   a3 = fmaf(x3.y, w[i+3].y, a3);
                a3 = fmaf(x3.z, w[i+3].z, a3);   a3 = fmaf(x3.w, w[i+3].w, a3);
            }
            const float ghb = ((a0 + a1) + (a2 + a3)) + bj;

            if (j < 2 * H_) {
                s_rz[j] = gcur[u] + ghb;     // r,z preactivations
            } else {
                x_n[j - 2 * H_] = gcur[u];   // n-gate: keep x/h sides separate
                h_n[j - 2 * H_] = ghb;
            }
            __syncthreads();

            if (j < H_) {
                const float r = sigmoid_f(s_rz[j]);
                const float z = sigmoid_f(s_rz[j + H_]);
                const float n = tanh_f(x_n[j] + r * h_n[j]);
                const float hnew = (1.0f - z) * n + z * hbuf[j];
                hbuf[j] = hnew;
                if (STORE_H) hseq[((size_t)b * T_ + t) * H_ + j] = hnew;
            }
            __syncthreads();
        }
    }

    if (FINAL) {
        if (j < H_) hbuf[j] = fmaxf(hbuf[j], 0.0f);  // relu(last hidden)
        __syncthreads();
        if (j < 3) {
            float acc = fc_b[j];
            const float* fw = fc_w + j * H_;
#pragma unroll
            for (int k = 0; k < H_; k++) acc = fmaf(hbuf[k], fw[k], acc);
            out[b * 3 + j] = acc;
        }
    }
}

// ---------------------------------------------------------------------------
extern "C" void kernel_launch(void* const* d_in, const int* in_sizes, int n_in,
                              void* d_out, int out_size, void* d_ws, size_t ws_size,
                              hipStream_t stream)
{
    const int*   x    = (const int*)  d_in[0];
    const float* emb  = (const float*)d_in[1];
    const float* W_ih = (const float*)d_in[2];  // [2,384,128]
    const float* W_hh = (const float*)d_in[3];  // [2,384,128]
    const float* b_ih = (const float*)d_in[4];  // [2,384]
    const float* b_hh = (const float*)d_in[5];  // [2,384]
    const float* fc_w = (const float*)d_in[6];  // [3,128]
    const float* fc_b = (const float*)d_in[7];  // [3]
    float* out = (float*)d_out;

    const int M = B_ * T_;                                   // 131072 rows
    const size_t gx_f32 = (size_t)M * G3_ * sizeof(float);   // 201.3 MB

    float* gx = (float*)d_ws;
    float* h1 = (float*)((char*)d_ws + gx_f32);              // 67.1 MB

    dim3 ggx(G3_ / TN, M / TM);   // (3, 1024)
    dim3 bgx(256);
    dim3 grec(B_), brec(G3_);

    hipLaunchKernelGGL((gx_gemm<true>), ggx, bgx, 0, stream,
                       nullptr, x, emb, W_ih, b_ih, gx);
    hipLaunchKernelGGL((gru_rec<true, false>), grec, brec, 0, stream,
                       gx, W_hh, b_hh, h1, nullptr, nullptr, nullptr);
    hipLaunchKernelGGL((gx_gemm<false>), ggx, bgx, 0, stream,
                       h1, nullptr, nullptr, W_ih + G3_ * H_, b_ih + G3_, gx);
    hipLaunchKernelGGL((gru_rec<false, true>), grec, brec, 0, stream,
                       gx, W_hh + G3_ * H_, b_hh + G3_, nullptr, fc_w, fc_b, out);
}

// Round 7
// 1126.404 us; speedup vs baseline: 1.1697x; 1.1697x over previous
//
#include <hip/hip_runtime.h>
#include <hip/hip_bf16.h>

#define B_   256
#define T_   512
#define H_   128
#define G3_  384

// ---- tiled GEMM config ----
#define TM   128
#define TN   128
#define TK   32
#define LDA  132

__device__ __forceinline__ float sigmoid_f(float x) {
    return 1.0f / (1.0f + __expf(-x));
}
__device__ __forceinline__ float tanh_f(float x) {
    return 1.0f - 2.0f / (__expf(2.0f * x) + 1.0f);
}

// Butterfly sum over each aligned 8-lane group, pure DPP (no LDS pipe),
// result valid on ALL lanes. quad_perm xor1, quad_perm xor2, row_half_mirror
// (lane i <-> 7-i within each 8-half: crosses the quad boundary inside the
// group, never the group boundary).
__device__ __forceinline__ float bfly_fold8(float v) {
    int x;
    x = __builtin_amdgcn_update_dpp(0, __float_as_int(v), 0x0B1, 0xF, 0xF, true);
    v += __int_as_float(x);   // xor 1
    x = __builtin_amdgcn_update_dpp(0, __float_as_int(v), 0x04E, 0xF, 0xF, true);
    v += __int_as_float(x);   // xor 2
    x = __builtin_amdgcn_update_dpp(0, __float_as_int(v), 0x141, 0xF, 0xF, true);
    v += __int_as_float(x);   // other quad (half mirror)
    return v;
}

#define DOT4(acc, hv, wv)                                        \
    acc = fmaf((hv).x, (wv).x, acc);                             \
    acc = fmaf((hv).y, (wv).y, acc);                             \
    acc = fmaf((hv).z, (wv).z, acc);                             \
    acc = fmaf((hv).w, (wv).w, acc);

// ---------------------------------------------------------------------------
// gx GEMM (unchanged from R2 — ~150 us, healthy)
// ---------------------------------------------------------------------------
template<bool GATHER>
__global__ __launch_bounds__(256, 2)
void gx_gemm(const float* __restrict__ X,
             const int*   __restrict__ idx,
             const float* __restrict__ emb,
             const float* __restrict__ W,     // [384,128] row-major
             const float* __restrict__ bias,  // [384]
             float*       __restrict__ gx)    // [M,384]
{
    __shared__ __align__(16) float As[2][TK][LDA];
    __shared__ __align__(16) float Bs[2][TK][LDA];

    const int tid = threadIdx.x;
    const int tn  = tid & 15;
    const int tm  = tid >> 4;
    const int n0  = blockIdx.x * TN;
    const int m0  = blockIdx.y * TM;

    const int q  = tid & 7;
    const float* rowA[4];
    const float* rowB[4];
#pragma unroll
    for (int s = 0; s < 4; s++) {
        const int r = (tid >> 3) + 32 * s;
        rowA[s] = GATHER ? (emb + (size_t)idx[m0 + r] * H_)
                         : (X + (size_t)(m0 + r) * H_);
        rowB[s] = W + (size_t)(n0 + r) * H_;
    }

    float4 stA[4], stB[4];
    auto load_chunk = [&](int kc) {
#pragma unroll
        for (int s = 0; s < 4; s++) {
            stA[s] = *(const float4*)(rowA[s] + kc + q * 4);
            stB[s] = *(const float4*)(rowB[s] + kc + q * 4);
        }
    };
    auto store_chunk = [&](int buf) {
#pragma unroll
        for (int s = 0; s < 4; s++) {
            const int r = (tid >> 3) + 32 * s;
#pragma unroll
            for (int d = 0; d < 4; d++) {
                As[buf][q * 4 + d][r] = ((const float*)&stA[s])[d];
                Bs[buf][q * 4 + d][r] = ((const float*)&stB[s])[d];
            }
        }
    };

    float4 acc[2][2][4];
#pragma unroll
    for (int a = 0; a < 2; a++)
#pragma unroll
        for (int b = 0; b < 2; b++)
#pragma unroll
            for (int c = 0; c < 4; c++) acc[a][b][c] = make_float4(0.f, 0.f, 0.f, 0.f);

    load_chunk(0);
    store_chunk(0);
    __syncthreads();

    for (int c = 0; c < 4; c++) {
        if (c < 3) load_chunk((c + 1) * TK);
        const int buf = c & 1;
#pragma unroll 4
        for (int k = 0; k < TK; k++) {
            float4 a0 = *(const float4*)&As[buf][k][tm * 4];
            float4 a1 = *(const float4*)&As[buf][k][64 + tm * 4];
            float4 b0 = *(const float4*)&Bs[buf][k][tn * 4];
            float4 b1 = *(const float4*)&Bs[buf][k][64 + tn * 4];
            float4 av[2] = {a0, a1}, bv[2] = {b0, b1};
#pragma unroll
            for (int mg = 0; mg < 2; mg++)
#pragma unroll
                for (int mi = 0; mi < 4; mi++) {
                    const float am = ((const float*)&av[mg])[mi];
#pragma unroll
                    for (int ng = 0; ng < 2; ng++) {
                        acc[mg][ng][mi].x = fmaf(am, bv[ng].x, acc[mg][ng][mi].x);
                        acc[mg][ng][mi].y = fmaf(am, bv[ng].y, acc[mg][ng][mi].y);
                        acc[mg][ng][mi].z = fmaf(am, bv[ng].z, acc[mg][ng][mi].z);
                        acc[mg][ng][mi].w = fmaf(am, bv[ng].w, acc[mg][ng][mi].w);
                    }
                }
        }
        if (c < 3) {
            store_chunk(buf ^ 1);
            __syncthreads();
        }
    }

    const float4 bb0 = *(const float4*)(bias + n0 + tn * 4);
    const float4 bb1 = *(const float4*)(bias + n0 + 64 + tn * 4);
#pragma unroll
    for (int mg = 0; mg < 2; mg++)
#pragma unroll
        for (int mi = 0; mi < 4; mi++) {
            const int m = m0 + mg * 64 + tm * 4 + mi;
            float* dst = gx + (size_t)m * G3_ + n0;
            float4 v0 = acc[mg][0][mi];
            v0.x += bb0.x; v0.y += bb0.y; v0.z += bb0.z; v0.w += bb0.w;
            float4 v1 = acc[mg][1][mi];
            v1.x += bb1.x; v1.y += bb1.y; v1.z += bb1.z; v1.w += bb1.w;
            *(float4*)(dst + tn * 4) = v0;
            *(float4*)(dst + 64 + tn * 4) = v1;
        }
}

// ---------------------------------------------------------------------------
// GRU recurrence, split-K. One block (1024 thr) per batch row.
// Thread (jg = tid>>3, ks = tid&7): owns W_hh rows 3jg..3jg+2, cols
// ks*16..+15 = 48 floats in VGPRs (~78 live total, under the ~84 budget the
// allocator enforces — see R2-R5 journal). Per step: 4 b128 h-reads
// (bank-swizzled, 8-lane broadcast, conflict-free), 48 FMA, butterfly-fold
// over the 8 ks-lanes (DPP, no LDS), gates on threads 0..127.
// LDS issue/step: 64 b128-instr (~768 cyc) vs 192 (~2300 cyc) in R2-R5 —
// that instr count was the measured bottleneck (2390 cyc/step).
//
// h2 swizzle: h[k] stored at word ((k>>2)&3)*32 + (k>>4)*4 + (k&3), so read
// instr i (words i*32 + ks*4 ..+3) gives 8 distinct b128 addrs covering all
// 32 banks, 8 lanes broadcast each.
// ---------------------------------------------------------------------------
template<bool STORE_H, bool FINAL>
__global__ __launch_bounds__(1024)
void gru_rec(const float* __restrict__ gx,   // [B,T,384]
             const float* __restrict__ Whh,  // [384,128]
             const float* __restrict__ bhh,  // [384]
             float*       __restrict__ hseq, // [B,T,128] if STORE_H
             const float* __restrict__ fc_w, // [3,128]  if FINAL
             const float* __restrict__ fc_b, // [3]      if FINAL
             float*       __restrict__ out)  // [B,3]    if FINAL
{
    __shared__ __align__(16) float h2[H_];   // swizzled h
    __shared__ float gh[G3_];

    const int tid = threadIdx.x;
    const int b   = blockIdx.x;
    const int jg  = tid >> 3;      // 0..127
    const int ks  = tid & 7;       // 0..7
    const int j0  = jg * 3;

    // --- W_hh fragment: 12 float4 in named registers ---
    const float4* w0p = (const float4*)(Whh + (size_t)(j0    ) * H_ + ks * 16);
    const float4* w1p = (const float4*)(Whh + (size_t)(j0 + 1) * H_ + ks * 16);
    const float4* w2p = (const float4*)(Whh + (size_t)(j0 + 2) * H_ + ks * 16);
    float4 w00 = w0p[0], w01 = w0p[1], w02 = w0p[2], w03 = w0p[3];
    float4 w10 = w1p[0], w11 = w1p[1], w12 = w1p[2], w13 = w1p[3];
    float4 w20 = w2p[0], w21 = w2p[1], w22 = w2p[2], w23 = w2p[3];

    // --- gate-thread state (tid < 128) ---
    const bool gate = (tid < H_);
    float bhr = 0.f, bhz = 0.f, bhn = 0.f;
    float gr = 0.f, gz = 0.f, gn = 0.f;
    float h_old = 0.f;
    int   hw = 0;
    const float* gxb = gx + (size_t)b * T_ * G3_;
    if (gate) {
        bhr = bhh[tid]; bhz = bhh[tid + H_]; bhn = bhh[tid + 2 * H_];
        gr = gxb[tid]; gz = gxb[tid + H_]; gn = gxb[tid + 2 * H_];
        hw = ((tid >> 2) & 3) * 32 + (tid >> 4) * 4 + (tid & 3);
        h2[tid] = 0.0f;   // zeros are swizzle-invariant
    }
    __syncthreads();

    const int hb = ks * 4;  // base word of this thread's k-slice (swizzled)

    for (int t = 0; t < T_; t++) {
        // prefetch next step's gx (covered by this step's compute)
        float gr2 = 0.f, gz2 = 0.f, gn2 = 0.f;
        if (gate) {
            const float* gnx = gxb + (size_t)min(t + 1, T_ - 1) * G3_;
            gr2 = gnx[tid]; gz2 = gnx[tid + H_]; gn2 = gnx[tid + 2 * H_];
        }

        // ---- phase A: partial dots; hv read one float4 at a time to keep
        //      live registers under the allocator's budget ----
        float p0 = 0.f, p1 = 0.f, p2 = 0.f;
        {
            float4 hv;
            hv = *(const float4*)&h2[hb];
            DOT4(p0, hv, w00) DOT4(p1, hv, w10) DOT4(p2, hv, w20)
            hv = *(const float4*)&h2[32 + hb];
            DOT4(p0, hv, w01) DOT4(p1, hv, w11) DOT4(p2, hv, w21)
            hv = *(const float4*)&h2[64 + hb];
            DOT4(p0, hv, w02) DOT4(p1, hv, w12) DOT4(p2, hv, w22)
            hv = *(const float4*)&h2[96 + hb];
            DOT4(p0, hv, w03) DOT4(p1, hv, w13) DOT4(p2, hv, w23)
        }

        p0 = bfly_fold8(p0);
        p1 = bfly_fold8(p1);
        p2 = bfly_fold8(p2);
        if (ks == 0) {
            gh[j0] = p0; gh[j0 + 1] = p1; gh[j0 + 2] = p2;
        }
        __syncthreads();

        // ---- phase B: gates on threads 0..127 ----
        if (gate) {
            const float ghr = gh[tid] + bhr;
            const float ghz = gh[tid + H_] + bhz;
            const float ghn = gh[tid + 2 * H_] + bhn;
            const float r = sigmoid_f(gr + ghr);
            const float z = sigmoid_f(gz + ghz);
            const float n = tanh_f(gn + r * ghn);
            h_old = (1.0f - z) * n + z * h_old;
            h2[hw] = h_old;
            if (STORE_H) hseq[((size_t)b * T_ + t) * H_ + tid] = h_old;
            gr = gr2; gz = gz2; gn = gn2;
        }
        __syncthreads();
    }

    if (FINAL) {
        if (gate) gh[tid] = fmaxf(h_old, 0.0f);   // relu(last hidden)
        __syncthreads();
        if (tid < 3) {
            float acc = fc_b[tid];
            const float* fw = fc_w + tid * H_;
#pragma unroll
            for (int k = 0; k < H_; k++) acc = fmaf(gh[k], fw[k], acc);
            out[b * 3 + tid] = acc;
        }
    }
}

// ---------------------------------------------------------------------------
extern "C" void kernel_launch(void* const* d_in, const int* in_sizes, int n_in,
                              void* d_out, int out_size, void* d_ws, size_t ws_size,
                              hipStream_t stream)
{
    const int*   x    = (const int*)  d_in[0];
    const float* emb  = (const float*)d_in[1];
    const float* W_ih = (const float*)d_in[2];  // [2,384,128]
    const float* W_hh = (const float*)d_in[3];  // [2,384,128]
    const float* b_ih = (const float*)d_in[4];  // [2,384]
    const float* b_hh = (const float*)d_in[5];  // [2,384]
    const float* fc_w = (const float*)d_in[6];  // [3,128]
    const float* fc_b = (const float*)d_in[7];  // [3]
    float* out = (float*)d_out;

    const int M = B_ * T_;                                   // 131072 rows
    const size_t gx_f32 = (size_t)M * G3_ * sizeof(float);   // 201.3 MB

    float* gx = (float*)d_ws;
    float* h1 = (float*)((char*)d_ws + gx_f32);              // 67.1 MB

    dim3 ggx(G3_ / TN, M / TM);   // (3, 1024)
    dim3 bgx(256);
    dim3 grec(B_), brec(1024);

    hipLaunchKernelGGL((gx_gemm<true>), ggx, bgx, 0, stream,
                       nullptr, x, emb, W_ih, b_ih, gx);
    hipLaunchKernelGGL((gru_rec<true, false>), grec, brec, 0, stream,
                       gx, W_hh, b_hh, h1, nullptr, nullptr, nullptr);
    hipLaunchKernelGGL((gx_gemm<false>), ggx, bgx, 0, stream,
                       h1, nullptr, nullptr, W_ih + G3_ * H_, b_ih + G3_, gx);
    hipLaunchKernelGGL((gru_rec<false, true>), grec, brec, 0, stream,
                       gx, W_hh + G3_ * H_, b_hh + G3_, nullptr, fc_w, fc_b, out);
}

// Round 8
// 1071.145 us; speedup vs baseline: 1.2300x; 1.0516x over previous
//
#include <hip/hip_runtime.h>
#include <hip/hip_bf16.h>

#define B_   256
#define T_   512
#define H_   128
#define G3_  384

// ---- tiled GEMM config ----
#define TM   128
#define TN   128
#define TK   32
#define LDA  132

// dynamic-LDS clamp for gru_rec: force 1 block/CU so the scheduler's
// occupancy target drops to 4 waves/EU -> 128-VGPR budget (see R7 journal)
#define REC_LDS_BYTES 102400

__device__ __forceinline__ float sigmoid_f(float x) {
    return 1.0f / (1.0f + __expf(-x));
}
__device__ __forceinline__ float tanh_f(float x) {
    return 1.0f - 2.0f / (__expf(2.0f * x) + 1.0f);
}

// Butterfly sum over each aligned 8-lane group, pure DPP (no LDS pipe),
// result valid on ALL lanes: quad_perm xor1, quad_perm xor2, row_half_mirror.
__device__ __forceinline__ float bfly_fold8(float v) {
    int x;
    x = __builtin_amdgcn_update_dpp(0, __float_as_int(v), 0x0B1, 0xF, 0xF, true);
    v += __int_as_float(x);   // xor 1
    x = __builtin_amdgcn_update_dpp(0, __float_as_int(v), 0x04E, 0xF, 0xF, true);
    v += __int_as_float(x);   // xor 2
    x = __builtin_amdgcn_update_dpp(0, __float_as_int(v), 0x141, 0xF, 0xF, true);
    v += __int_as_float(x);   // other quad (half mirror)
    return v;
}

#define DOT4(acc, hv, wv)                                        \
    acc = fmaf((hv).x, (wv).x, acc);                             \
    acc = fmaf((hv).y, (wv).y, acc);                             \
    acc = fmaf((hv).z, (wv).z, acc);                             \
    acc = fmaf((hv).w, (wv).w, acc);

// ---------------------------------------------------------------------------
// gx GEMM (unchanged from R2 — ~150 us, healthy)
// ---------------------------------------------------------------------------
template<bool GATHER>
__global__ __launch_bounds__(256, 2)
void gx_gemm(const float* __restrict__ X,
             const int*   __restrict__ idx,
             const float* __restrict__ emb,
             const float* __restrict__ W,     // [384,128] row-major
             const float* __restrict__ bias,  // [384]
             float*       __restrict__ gx)    // [M,384]
{
    __shared__ __align__(16) float As[2][TK][LDA];
    __shared__ __align__(16) float Bs[2][TK][LDA];

    const int tid = threadIdx.x;
    const int tn  = tid & 15;
    const int tm  = tid >> 4;
    const int n0  = blockIdx.x * TN;
    const int m0  = blockIdx.y * TM;

    const int q  = tid & 7;
    const float* rowA[4];
    const float* rowB[4];
#pragma unroll
    for (int s = 0; s < 4; s++) {
        const int r = (tid >> 3) + 32 * s;
        rowA[s] = GATHER ? (emb + (size_t)idx[m0 + r] * H_)
                         : (X + (size_t)(m0 + r) * H_);
        rowB[s] = W + (size_t)(n0 + r) * H_;
    }

    float4 stA[4], stB[4];
    auto load_chunk = [&](int kc) {
#pragma unroll
        for (int s = 0; s < 4; s++) {
            stA[s] = *(const float4*)(rowA[s] + kc + q * 4);
            stB[s] = *(const float4*)(rowB[s] + kc + q * 4);
        }
    };
    auto store_chunk = [&](int buf) {
#pragma unroll
        for (int s = 0; s < 4; s++) {
            const int r = (tid >> 3) + 32 * s;
#pragma unroll
            for (int d = 0; d < 4; d++) {
                As[buf][q * 4 + d][r] = ((const float*)&stA[s])[d];
                Bs[buf][q * 4 + d][r] = ((const float*)&stB[s])[d];
            }
        }
    };

    float4 acc[2][2][4];
#pragma unroll
    for (int a = 0; a < 2; a++)
#pragma unroll
        for (int b = 0; b < 2; b++)
#pragma unroll
            for (int c = 0; c < 4; c++) acc[a][b][c] = make_float4(0.f, 0.f, 0.f, 0.f);

    load_chunk(0);
    store_chunk(0);
    __syncthreads();

    for (int c = 0; c < 4; c++) {
        if (c < 3) load_chunk((c + 1) * TK);
        const int buf = c & 1;
#pragma unroll 4
        for (int k = 0; k < TK; k++) {
            float4 a0 = *(const float4*)&As[buf][k][tm * 4];
            float4 a1 = *(const float4*)&As[buf][k][64 + tm * 4];
            float4 b0 = *(const float4*)&Bs[buf][k][tn * 4];
            float4 b1 = *(const float4*)&Bs[buf][k][64 + tn * 4];
            float4 av[2] = {a0, a1}, bv[2] = {b0, b1};
#pragma unroll
            for (int mg = 0; mg < 2; mg++)
#pragma unroll
                for (int mi = 0; mi < 4; mi++) {
                    const float am = ((const float*)&av[mg])[mi];
#pragma unroll
                    for (int ng = 0; ng < 2; ng++) {
                        acc[mg][ng][mi].x = fmaf(am, bv[ng].x, acc[mg][ng][mi].x);
                        acc[mg][ng][mi].y = fmaf(am, bv[ng].y, acc[mg][ng][mi].y);
                        acc[mg][ng][mi].z = fmaf(am, bv[ng].z, acc[mg][ng][mi].z);
                        acc[mg][ng][mi].w = fmaf(am, bv[ng].w, acc[mg][ng][mi].w);
                    }
                }
        }
        if (c < 3) {
            store_chunk(buf ^ 1);
            __syncthreads();
        }
    }

    const float4 bb0 = *(const float4*)(bias + n0 + tn * 4);
    const float4 bb1 = *(const float4*)(bias + n0 + 64 + tn * 4);
#pragma unroll
    for (int mg = 0; mg < 2; mg++)
#pragma unroll
        for (int mi = 0; mi < 4; mi++) {
            const int m = m0 + mg * 64 + tm * 4 + mi;
            float* dst = gx + (size_t)m * G3_ + n0;
            float4 v0 = acc[mg][0][mi];
            v0.x += bb0.x; v0.y += bb0.y; v0.z += bb0.z; v0.w += bb0.w;
            float4 v1 = acc[mg][1][mi];
            v1.x += bb1.x; v1.y += bb1.y; v1.z += bb1.z; v1.w += bb1.w;
            *(float4*)(dst + tn * 4) = v0;
            *(float4*)(dst + 64 + tn * 4) = v1;
        }
}

// ---------------------------------------------------------------------------
// GRU recurrence, split-K (R7 structure). One block (1024 thr) per batch row.
// Thread (jg = tid>>3, ks = tid&7): owns W_hh rows 3jg..3jg+2, cols
// ks*16..+15 = 48 floats that must stay in VGPRs.
//
// R8 change: h2/gh live in DYNAMIC shared memory and the launch allocates
// 100 KB. This caps achievable occupancy at 1 block/CU (which the 256-block
// grid gives anyway), so the register allocator's occupancy target drops from
// 8 waves/EU (64-VGPR budget -> W sunk to per-step L1 reloads, 196 KB/CU/step
// = the 1875 cyc/step bottleneck, VGPR_Count=40) to 4 waves/EU (128-VGPR
// budget) -> W fragment stays register-resident.
// ---------------------------------------------------------------------------
template<bool STORE_H, bool FINAL>
__global__ __launch_bounds__(1024)
void gru_rec(const float* __restrict__ gx,   // [B,T,384]
             const float* __restrict__ Whh,  // [384,128]
             const float* __restrict__ bhh,  // [384]
             float*       __restrict__ hseq, // [B,T,128] if STORE_H
             const float* __restrict__ fc_w, // [3,128]  if FINAL
             const float* __restrict__ fc_b, // [3]      if FINAL
             float*       __restrict__ out)  // [B,3]    if FINAL
{
    extern __shared__ __align__(16) float smem[];
    float* h2 = smem;          // [128] swizzled h
    float* gh = smem + H_;     // [384]

    const int tid = threadIdx.x;
    const int b   = blockIdx.x;
    const int jg  = tid >> 3;      // 0..127
    const int ks  = tid & 7;       // 0..7
    const int j0  = jg * 3;

    // --- W_hh fragment: 12 float4 in named registers ---
    const float4* w0p = (const float4*)(Whh + (size_t)(j0    ) * H_ + ks * 16);
    const float4* w1p = (const float4*)(Whh + (size_t)(j0 + 1) * H_ + ks * 16);
    const float4* w2p = (const float4*)(Whh + (size_t)(j0 + 2) * H_ + ks * 16);
    float4 w00 = w0p[0], w01 = w0p[1], w02 = w0p[2], w03 = w0p[3];
    float4 w10 = w1p[0], w11 = w1p[1], w12 = w1p[2], w13 = w1p[3];
    float4 w20 = w2p[0], w21 = w2p[1], w22 = w2p[2], w23 = w2p[3];

    // --- gate-thread state (tid < 128) ---
    const bool gate = (tid < H_);
    float bhr = 0.f, bhz = 0.f, bhn = 0.f;
    float gr = 0.f, gz = 0.f, gn = 0.f;
    float h_old = 0.f;
    int   hw = 0;
    const float* gxb = gx + (size_t)b * T_ * G3_;
    if (gate) {
        bhr = bhh[tid]; bhz = bhh[tid + H_]; bhn = bhh[tid + 2 * H_];
        gr = gxb[tid]; gz = gxb[tid + H_]; gn = gxb[tid + 2 * H_];
        hw = ((tid >> 2) & 3) * 32 + (tid >> 4) * 4 + (tid & 3);
        h2[tid] = 0.0f;   // zeros are swizzle-invariant
    }
    __syncthreads();

    const int hb = ks * 4;  // base word of this thread's k-slice (swizzled)

    for (int t = 0; t < T_; t++) {
        // prefetch next step's gx (covered by this step's compute)
        float gr2 = 0.f, gz2 = 0.f, gn2 = 0.f;
        if (gate) {
            const float* gnx = gxb + (size_t)min(t + 1, T_ - 1) * G3_;
            gr2 = gnx[tid]; gz2 = gnx[tid + H_]; gn2 = gnx[tid + 2 * H_];
        }

        // ---- phase A: partial dots over this thread's k-slice ----
        float p0 = 0.f, p1 = 0.f, p2 = 0.f;
        {
            float4 hv;
            hv = *(const float4*)&h2[hb];
            DOT4(p0, hv, w00) DOT4(p1, hv, w10) DOT4(p2, hv, w20)
            hv = *(const float4*)&h2[32 + hb];
            DOT4(p0, hv, w01) DOT4(p1, hv, w11) DOT4(p2, hv, w21)
            hv = *(const float4*)&h2[64 + hb];
            DOT4(p0, hv, w02) DOT4(p1, hv, w12) DOT4(p2, hv, w22)
            hv = *(const float4*)&h2[96 + hb];
            DOT4(p0, hv, w03) DOT4(p1, hv, w13) DOT4(p2, hv, w23)
        }

        p0 = bfly_fold8(p0);
        p1 = bfly_fold8(p1);
        p2 = bfly_fold8(p2);
        if (ks == 0) {
            gh[j0] = p0; gh[j0 + 1] = p1; gh[j0 + 2] = p2;
        }
        __syncthreads();

        // ---- phase B: gates on threads 0..127 ----
        if (gate) {
            const float ghr = gh[tid] + bhr;
            const float ghz = gh[tid + H_] + bhz;
            const float ghn = gh[tid + 2 * H_] + bhn;
            const float r = sigmoid_f(gr + ghr);
            const float z = sigmoid_f(gz + ghz);
            const float n = tanh_f(gn + r * ghn);
            h_old = (1.0f - z) * n + z * h_old;
            h2[hw] = h_old;
            if (STORE_H) hseq[((size_t)b * T_ + t) * H_ + tid] = h_old;
            gr = gr2; gz = gz2; gn = gn2;
        }
        __syncthreads();
    }

    if (FINAL) {
        if (gate) gh[tid] = fmaxf(h_old, 0.0f);   // relu(last hidden)
        __syncthreads();
        if (tid < 3) {
            float acc = fc_b[tid];
            const float* fw = fc_w + tid * H_;
#pragma unroll
            for (int k = 0; k < H_; k++) acc = fmaf(gh[k], fw[k], acc);
            out[b * 3 + tid] = acc;
        }
    }
}

// ---------------------------------------------------------------------------
extern "C" void kernel_launch(void* const* d_in, const int* in_sizes, int n_in,
                              void* d_out, int out_size, void* d_ws, size_t ws_size,
                              hipStream_t stream)
{
    const int*   x    = (const int*)  d_in[0];
    const float* emb  = (const float*)d_in[1];
    const float* W_ih = (const float*)d_in[2];  // [2,384,128]
    const float* W_hh = (const float*)d_in[3];  // [2,384,128]
    const float* b_ih = (const float*)d_in[4];  // [2,384]
    const float* b_hh = (const float*)d_in[5];  // [2,384]
    const float* fc_w = (const float*)d_in[6];  // [3,128]
    const float* fc_b = (const float*)d_in[7];  // [3]
    float* out = (float*)d_out;

    const int M = B_ * T_;                                   // 131072 rows
    const size_t gx_f32 = (size_t)M * G3_ * sizeof(float);   // 201.3 MB

    float* gx = (float*)d_ws;
    float* h1 = (float*)((char*)d_ws + gx_f32);              // 67.1 MB

    dim3 ggx(G3_ / TN, M / TM);   // (3, 1024)
    dim3 bgx(256);
    dim3 grec(B_), brec(1024);

    hipLaunchKernelGGL((gx_gemm<true>), ggx, bgx, 0, stream,
                       nullptr, x, emb, W_ih, b_ih, gx);
    hipLaunchKernelGGL((gru_rec<true, false>), grec, brec, REC_LDS_BYTES, stream,
                       gx, W_hh, b_hh, h1, nullptr, nullptr, nullptr);
    hipLaunchKernelGGL((gx_gemm<false>), ggx, bgx, 0, stream,
                       h1, nullptr, nullptr, W_ih + G3_ * H_, b_ih + G3_, gx);
    hipLaunchKernelGGL((gru_rec<false, true>), grec, brec, REC_LDS_BYTES, stream,
                       gx, W_hh + G3_ * H_, b_hh + G3_, nullptr, fc_w, fc_b, out);
}